// Round 9
// baseline (194.992 us; speedup 1.0000x reference)
//
#include <hip/hip_runtime.h>
#include <hip/hip_bf16.h>
#include <cmath>

typedef _Float16 half8 __attribute__((ext_vector_type(8)));
typedef _Float16 half4 __attribute__((ext_vector_type(4)));
typedef float f32x4 __attribute__((ext_vector_type(4)));

// Geometry: B=4, S=4096, D=1024, D_H=1024 -> M=16384, K=1024, N=3072
#define M_DIM 16384
#define K_DIM 1024
#define N_DIM 3072
#define S_LEN 4096
#define NCHUNK 128
#define CLEN 32

#define OT_STRIDE 136   // epilogue LDS row stride (f16); 272B = 16B-aligned

__device__ __forceinline__ float fast_sigmoid(float x) {
    return __builtin_amdgcn_rcpf(1.0f + __expf(-x));
}
__device__ __forceinline__ float fast_tanh(float x) {
    float t = __expf(-2.0f * __builtin_fabsf(x));
    float y = (1.0f - t) * __builtin_amdgcn_rcpf(1.0f + t);
    return __builtin_copysignf(y, x);
}

// ---------------- fused cast kernel ----------------
// blocks [0,16384): x fp32 -> f16 (4 elems/thread)
// blocks [16384,17152): W (1024,3072) fp32 -> Wt (3072,1024) f16 via LDS transpose
__global__ void k_cast(const float* __restrict__ x, _Float16* __restrict__ xb,
                       const float* __restrict__ W, _Float16* __restrict__ Wt) {
    __shared__ float t[64][65];
    if (blockIdx.x < 16384) {
        int i = blockIdx.x * blockDim.x + threadIdx.x;
        float4 v = reinterpret_cast<const float4*>(x)[i];
        half4 h;
        h.x = (_Float16)v.x; h.y = (_Float16)v.y;
        h.z = (_Float16)v.z; h.w = (_Float16)v.w;
        reinterpret_cast<half4*>(xb)[i] = h;
    } else {
        const int wb = blockIdx.x - 16384;
        const int k0 = (wb / 48) * 64;
        const int n0 = (wb % 48) * 64;
        const int c  = threadIdx.x & 63;
        const int r0 = threadIdx.x >> 6;
        #pragma unroll
        for (int i = 0; i < 16; ++i) {
            int r = r0 + i * 4;
            t[r][c] = W[(size_t)(k0 + r) * N_DIM + n0 + c];
        }
        __syncthreads();
        #pragma unroll
        for (int i = 0; i < 16; ++i) {
            int r = r0 + i * 4;
            Wt[(size_t)(n0 + r) * K_DIM + k0 + c] = (_Float16)t[c][r];
        }
    }
}

// ---------------- GEMM: 128x128 tile, 4 waves, single 32KB buffer, 3 blocks/CU ----
// (256,3) NOT (256,4): unified VGPR+AGPR need ~140; cap 128 spills acc (round-6).
// At the m97-structure ceiling for K=1024 (~912 TF); epilogue stores proj+bias f16.
__global__ __launch_bounds__(256, 3) void k_gemm(
    const _Float16* __restrict__ A,
    const _Float16* __restrict__ Bt,
    const float* __restrict__ bias,
    _Float16* __restrict__ G)
{
    __shared__ _Float16 lds[128 * OT_STRIDE];   // GEMM uses [0,16384); epilogue all

    const int tid  = threadIdx.x;
    const int lane = tid & 63;
    const int w    = tid >> 6;     // 0..3
    const int wr   = w >> 1;       // 0..1 (M half)
    const int wc   = w & 1;        // 0..1 (N half)

    // XCD swizzle (3072 % 8 == 0); N-major within M-panel for A L2 reuse.
    const int bid   = blockIdx.x;
    const int wg    = (bid & 7) * 384 + (bid >> 3);
    const int tileM = (wg / 24) * 128;
    const int tileN = (wg % 24) * 128;

    // Staging: LDS dest linear; global source column pre-swizzled (rule #21).
    const int l3   = lane >> 3;
    const int c8   = lane & 7;
    const int scol = ((c8 ^ l3) << 3);
    const _Float16* gA = A  + (size_t)(tileM + w * 32 + l3) * K_DIM + scol;
    const _Float16* gB = Bt + (size_t)(tileN + w * 32 + l3) * K_DIM + scol;
    _Float16* const sA = lds + w * 2048;
    _Float16* const sB = lds + 8192 + w * 2048;

    // Fragment reads: col-group ^ (row&7); row&7 == l15&7.
    const int l15 = lane & 15;
    const int hi  = lane >> 4;
    const int swz = (l15 & 7) << 3;
    const int o0  = (hi * 8)      ^ swz;
    const int o1  = (32 + hi * 8) ^ swz;
    const _Float16* arow = lds + (wr * 64 + l15) * 64;
    const _Float16* brow = lds + 8192 + (wc * 64 + l15) * 64;

    f32x4 acc[4][4] = {};

#define GL(SRC, DST) __builtin_amdgcn_global_load_lds( \
        (const __attribute__((address_space(1))) void*)(SRC), \
        (__attribute__((address_space(3))) void*)(DST), 16, 0, 0)

#define STAGE(kt) do { \
        const _Float16* ga_ = gA + (size_t)(kt) * 64; \
        const _Float16* gb_ = gB + (size_t)(kt) * 64; \
        GL(ga_,                       sA);        \
        GL(ga_ + (size_t) 8 * K_DIM,  sA + 512);  \
        GL(ga_ + (size_t)16 * K_DIM,  sA + 1024); \
        GL(ga_ + (size_t)24 * K_DIM,  sA + 1536); \
        GL(gb_,                       sB);        \
        GL(gb_ + (size_t) 8 * K_DIM,  sB + 512);  \
        GL(gb_ + (size_t)16 * K_DIM,  sB + 1024); \
        GL(gb_ + (size_t)24 * K_DIM,  sB + 1536); \
    } while (0)

#define SCHED0() __builtin_amdgcn_sched_barrier(0)

    // Prologue
    STAGE(0);
    asm volatile("s_waitcnt vmcnt(0)" ::: "memory");
    __builtin_amdgcn_s_barrier();
    asm volatile("" ::: "memory");

    #pragma unroll 1
    for (int kt = 0; kt < 16; ++kt) {
        half8 a[4][2], b[4][2];
        #pragma unroll
        for (int m = 0; m < 4; ++m) {
            a[m][0] = *(const half8*)(arow + m * 1024 + o0);
            a[m][1] = *(const half8*)(arow + m * 1024 + o1);
            b[m][0] = *(const half8*)(brow + m * 1024 + o0);
            b[m][1] = *(const half8*)(brow + m * 1024 + o1);
        }
        asm volatile("s_waitcnt lgkmcnt(0)" ::: "memory");
        SCHED0();
        __builtin_amdgcn_s_barrier();      // all waves done reading tile kt

        if (kt < 15) STAGE(kt + 1);        // overwrite buffer; lands under MFMA
        SCHED0();

        __builtin_amdgcn_s_setprio(1);
        #pragma unroll
        for (int m = 0; m < 4; ++m)
            #pragma unroll
            for (int n = 0; n < 4; ++n)
                acc[m][n] = __builtin_amdgcn_mfma_f32_16x16x32_f16(
                    a[m][0], b[n][0], acc[m][n], 0, 0, 0);
        #pragma unroll
        for (int m = 0; m < 4; ++m)
            #pragma unroll
            for (int n = 0; n < 4; ++n)
                acc[m][n] = __builtin_amdgcn_mfma_f32_16x16x32_f16(
                    a[m][1], b[n][1], acc[m][n], 0, 0, 0);
        __builtin_amdgcn_s_setprio(0);
        SCHED0();

        if (kt < 15) {
            asm volatile("s_waitcnt vmcnt(0)" ::: "memory");
            __builtin_amdgcn_s_barrier();  // tile kt+1 fully landed
            asm volatile("" ::: "memory");
        }
    }
#undef STAGE
#undef GL

    // Epilogue: bias add -> f16 into LDS, then full 256B-segment coalesced store.
    // C/D frag layout: row = (lane>>4)*4 + r, col = lane&15.
    #pragma unroll
    for (int j = 0; j < 4; ++j) {
        const int n  = wc * 64 + j * 16 + l15;
        const float bn = bias[tileN + n];
        #pragma unroll
        for (int i = 0; i < 4; ++i) {
            const int rb = wr * 64 + i * 16 + hi * 4;
            #pragma unroll
            for (int r = 0; r < 4; ++r)
                lds[(rb + r) * OT_STRIDE + n] = (_Float16)(acc[i][j][r] + bn);
        }
    }
    __syncthreads();
    {
        const int row = tid >> 4;           // 0..15
        const int col = (tid & 15) * 8;     // 0..120
        #pragma unroll
        for (int itr = 0; itr < 8; ++itr) {
            const int rr = row + itr * 16;
            half8 vv = *(const half8*)(lds + rr * OT_STRIDE + col);
            *(half8*)(G + (size_t)(tileM + rr) * N_DIM + tileN + col) = vv;
        }
    }
}

// ---------------- chunked scan: CLEN=32, NCHUNK=128 -> 512 blocks (2 waves/SIMD)
__global__ void k_scan1(const _Float16* __restrict__ G,
                        float* __restrict__ sumA, float* __restrict__ sumH) {
    const int chunk = blockIdx.x & (NCHUNK - 1);
    const int b     = blockIdx.x >> 7;
    const int d0    = threadIdx.x * 4;

    const _Float16* base = G + (size_t)(b * S_LEN + chunk * CLEN) * N_DIM;
    float A[4], H[4];
    #pragma unroll
    for (int j = 0; j < 4; ++j) { A[j] = 1.0f; H[j] = 0.0f; }
    #pragma unroll 4
    for (int s = 0; s < CLEN; ++s) {
        half4 v0 = *(const half4*)(base + (size_t)s * N_DIM + d0);
        half4 v1 = *(const half4*)(base + (size_t)s * N_DIM + 1024 + d0);
        #pragma unroll
        for (int j = 0; j < 4; ++j) {
            float g0 = fast_tanh((float)v0[j]);
            float g1 = fast_sigmoid((float)v1[j]);
            float a  = 1.0f - g1;
            H[j] = fmaf(a, H[j], g0 * g1);
            A[j] *= a;
        }
    }
    const int cidx = (b * NCHUNK + chunk) * 1024 + d0;
    *(float4*)(sumA + cidx) = make_float4(A[0], A[1], A[2], A[3]);
    *(float4*)(sumH + cidx) = make_float4(H[0], H[1], H[2], H[3]);
}

__global__ void k_scan2(const float* __restrict__ sumA, const float* __restrict__ sumH,
                        float* __restrict__ pref) {
    const int c = blockIdx.x * blockDim.x + threadIdx.x;  // 0..4095
    const int b = c >> 10;
    const int d = c & 1023;
    float h = 0.0f;
    #pragma unroll 8
    for (int chunk = 0; chunk < NCHUNK; ++chunk) {
        const int idx = (b * NCHUNK + chunk) * 1024 + d;
        pref[idx] = h;
        h = fmaf(sumA[idx], h, sumH[idx]);
    }
}

__global__ void k_scan3(const _Float16* __restrict__ G,
                        const float* __restrict__ pref,
                        float* __restrict__ out) {
    const int chunk = blockIdx.x & (NCHUNK - 1);
    const int b     = blockIdx.x >> 7;
    const int d0    = threadIdx.x * 4;

    const _Float16* base = G + (size_t)(b * S_LEN + chunk * CLEN) * N_DIM;
    const int cidx = (b * NCHUNK + chunk) * 1024 + d0;
    float h[4];
    #pragma unroll
    for (int j = 0; j < 4; ++j) h[j] = pref[cidx + j];

    #pragma unroll 4
    for (int s = 0; s < CLEN; ++s) {
        half4 v0 = *(const half4*)(base + (size_t)s * N_DIM + d0);
        half4 v1 = *(const half4*)(base + (size_t)s * N_DIM + 1024 + d0);
        half4 v2 = *(const half4*)(base + (size_t)s * N_DIM + 2048 + d0);
        float4 o;
        #pragma unroll
        for (int j = 0; j < 4; ++j) {
            float g0 = fast_tanh((float)v0[j]);
            float g1 = fast_sigmoid((float)v1[j]);
            float g2 = fast_sigmoid((float)v2[j]);
            float a  = 1.0f - g1;
            h[j] = fmaf(a, h[j], g0 * g1);
            ((float*)&o)[j] = fast_tanh(h[j]) * g2;
        }
        *(float4*)(out + (size_t)(b * S_LEN + chunk * CLEN + s) * 1024 + d0) = o;
    }
}

extern "C" void kernel_launch(void* const* d_in, const int* in_sizes, int n_in,
                              void* d_out, int out_size, void* d_ws, size_t ws_size,
                              hipStream_t stream) {
    const float* x = (const float*)d_in[0];
    const float* W = (const float*)d_in[1];
    const float* b = (const float*)d_in[2];
    float* out = (float*)d_out;

    char* ws = (char*)d_ws;
    _Float16* xb = (_Float16*)ws;                               // 32 MB (dead after gemm)
    _Float16* Wt = (_Float16*)(ws + 33554432);                  // 6 MB
    _Float16* G  = (_Float16*)(ws + 33554432 + 6291456);        // 96 MB
    // Scan summaries alias xb's region (only live after k_gemm completes).
    float* sumA  = (float*)ws;                                  // 2 MB
    float* sumH  = sumA + 4096 * NCHUNK;                        // 2 MB
    float* pref  = sumH + 4096 * NCHUNK;                        // 2 MB

    k_cast <<<17152, 256, 0, stream>>>(x, xb, W, Wt);
    k_gemm <<<3072, 256, 0, stream>>>(xb, Wt, b, G);
    k_scan1<<<512, 256, 0, stream>>>(G, sumA, sumH);
    k_scan2<<<16,  256, 0, stream>>>(sumA, sumH, pref);
    k_scan3<<<512, 256, 0, stream>>>(G, pref, out);
    (void)in_sizes; (void)n_in; (void)out_size; (void)ws_size;
}

// Round 10
// 191.350 us; speedup vs baseline: 1.0190x; 1.0190x over previous
//
#include <hip/hip_runtime.h>
#include <hip/hip_bf16.h>
#include <cmath>

typedef _Float16 half8 __attribute__((ext_vector_type(8)));
typedef _Float16 half4 __attribute__((ext_vector_type(4)));
typedef float f32x4 __attribute__((ext_vector_type(4)));

// Geometry: B=4, S=4096, D=1024, D_H=1024 -> M=16384, K=1024, N=3072
#define M_DIM 16384
#define K_DIM 1024
#define N_DIM 3072
#define S_LEN 4096
#define NCHUNK 64
#define CLEN 64

#define OT_STRIDE 136   // epilogue LDS row stride (f16); 272B = 16B-aligned

__device__ __forceinline__ float fast_sigmoid(float x) {
    return __builtin_amdgcn_rcpf(1.0f + __expf(-x));
}
__device__ __forceinline__ float fast_tanh(float x) {
    float t = __expf(-2.0f * __builtin_fabsf(x));
    float y = (1.0f - t) * __builtin_amdgcn_rcpf(1.0f + t);
    return __builtin_copysignf(y, x);
}

// ---------------- fused cast kernel ----------------
// blocks [0,16384): x fp32 -> f16 (4 elems/thread)
// blocks [16384,17152): W (1024,3072) fp32 -> Wt (3072,1024) f16 via LDS transpose
__global__ void k_cast(const float* __restrict__ x, _Float16* __restrict__ xb,
                       const float* __restrict__ W, _Float16* __restrict__ Wt) {
    __shared__ float t[64][65];
    if (blockIdx.x < 16384) {
        int i = blockIdx.x * blockDim.x + threadIdx.x;
        float4 v = reinterpret_cast<const float4*>(x)[i];
        half4 h;
        h.x = (_Float16)v.x; h.y = (_Float16)v.y;
        h.z = (_Float16)v.z; h.w = (_Float16)v.w;
        reinterpret_cast<half4*>(xb)[i] = h;
    } else {
        const int wb = blockIdx.x - 16384;
        const int k0 = (wb / 48) * 64;
        const int n0 = (wb % 48) * 64;
        const int c  = threadIdx.x & 63;
        const int r0 = threadIdx.x >> 6;
        #pragma unroll
        for (int i = 0; i < 16; ++i) {
            int r = r0 + i * 4;
            t[r][c] = W[(size_t)(k0 + r) * N_DIM + n0 + c];
        }
        __syncthreads();
        #pragma unroll
        for (int i = 0; i < 16; ++i) {
            int r = r0 + i * 4;
            Wt[(size_t)(n0 + r) * K_DIM + k0 + c] = (_Float16)t[c][r];
        }
    }
}

// ---------------- GEMM: 128x128 tile, 4 waves, single 32KB buffer, 3 blocks/CU ----
// (256,3) NOT (256,4): unified VGPR+AGPR need ~140; cap 128 spills acc (round-6).
// At the m97-structure ceiling for K=1024 (~907 TF). Activations fused in the
// epilogue (best measured composite: activation cost hides worse in the scans).
__global__ __launch_bounds__(256, 3) void k_gemm(
    const _Float16* __restrict__ A,
    const _Float16* __restrict__ Bt,
    const float* __restrict__ bias,
    _Float16* __restrict__ G)
{
    __shared__ _Float16 lds[128 * OT_STRIDE];   // GEMM uses [0,16384); epilogue all

    const int tid  = threadIdx.x;
    const int lane = tid & 63;
    const int w    = tid >> 6;     // 0..3
    const int wr   = w >> 1;       // 0..1 (M half)
    const int wc   = w & 1;        // 0..1 (N half)

    // XCD swizzle (3072 % 8 == 0); N-major within M-panel for A L2 reuse.
    const int bid   = blockIdx.x;
    const int wg    = (bid & 7) * 384 + (bid >> 3);
    const int tileM = (wg / 24) * 128;
    const int tileN = (wg % 24) * 128;

    // Staging: LDS dest linear; global source column pre-swizzled (rule #21).
    const int l3   = lane >> 3;
    const int c8   = lane & 7;
    const int scol = ((c8 ^ l3) << 3);
    const _Float16* gA = A  + (size_t)(tileM + w * 32 + l3) * K_DIM + scol;
    const _Float16* gB = Bt + (size_t)(tileN + w * 32 + l3) * K_DIM + scol;
    _Float16* const sA = lds + w * 2048;
    _Float16* const sB = lds + 8192 + w * 2048;

    // Fragment reads: col-group ^ (row&7); row&7 == l15&7.
    const int l15 = lane & 15;
    const int hi  = lane >> 4;
    const int swz = (l15 & 7) << 3;
    const int o0  = (hi * 8)      ^ swz;
    const int o1  = (32 + hi * 8) ^ swz;
    const _Float16* arow = lds + (wr * 64 + l15) * 64;
    const _Float16* brow = lds + 8192 + (wc * 64 + l15) * 64;

    f32x4 acc[4][4] = {};

#define GL(SRC, DST) __builtin_amdgcn_global_load_lds( \
        (const __attribute__((address_space(1))) void*)(SRC), \
        (__attribute__((address_space(3))) void*)(DST), 16, 0, 0)

#define STAGE(kt) do { \
        const _Float16* ga_ = gA + (size_t)(kt) * 64; \
        const _Float16* gb_ = gB + (size_t)(kt) * 64; \
        GL(ga_,                       sA);        \
        GL(ga_ + (size_t) 8 * K_DIM,  sA + 512);  \
        GL(ga_ + (size_t)16 * K_DIM,  sA + 1024); \
        GL(ga_ + (size_t)24 * K_DIM,  sA + 1536); \
        GL(gb_,                       sB);        \
        GL(gb_ + (size_t) 8 * K_DIM,  sB + 512);  \
        GL(gb_ + (size_t)16 * K_DIM,  sB + 1024); \
        GL(gb_ + (size_t)24 * K_DIM,  sB + 1536); \
    } while (0)

#define SCHED0() __builtin_amdgcn_sched_barrier(0)

    // Prologue
    STAGE(0);
    asm volatile("s_waitcnt vmcnt(0)" ::: "memory");
    __builtin_amdgcn_s_barrier();
    asm volatile("" ::: "memory");

    #pragma unroll 1
    for (int kt = 0; kt < 16; ++kt) {
        half8 a[4][2], b[4][2];
        #pragma unroll
        for (int m = 0; m < 4; ++m) {
            a[m][0] = *(const half8*)(arow + m * 1024 + o0);
            a[m][1] = *(const half8*)(arow + m * 1024 + o1);
            b[m][0] = *(const half8*)(brow + m * 1024 + o0);
            b[m][1] = *(const half8*)(brow + m * 1024 + o1);
        }
        asm volatile("s_waitcnt lgkmcnt(0)" ::: "memory");
        SCHED0();
        __builtin_amdgcn_s_barrier();      // all waves done reading tile kt

        if (kt < 15) STAGE(kt + 1);        // overwrite buffer; lands under MFMA
        SCHED0();

        __builtin_amdgcn_s_setprio(1);
        #pragma unroll
        for (int m = 0; m < 4; ++m)
            #pragma unroll
            for (int n = 0; n < 4; ++n)
                acc[m][n] = __builtin_amdgcn_mfma_f32_16x16x32_f16(
                    a[m][0], b[n][0], acc[m][n], 0, 0, 0);
        #pragma unroll
        for (int m = 0; m < 4; ++m)
            #pragma unroll
            for (int n = 0; n < 4; ++n)
                acc[m][n] = __builtin_amdgcn_mfma_f32_16x16x32_f16(
                    a[m][1], b[n][1], acc[m][n], 0, 0, 0);
        __builtin_amdgcn_s_setprio(0);
        SCHED0();

        if (kt < 15) {
            asm volatile("s_waitcnt vmcnt(0)" ::: "memory");
            __builtin_amdgcn_s_barrier();  // tile kt+1 fully landed
            asm volatile("" ::: "memory");
        }
    }
#undef STAGE
#undef GL

    // Epilogue: bias + activation -> f16 into LDS, then full 256B-segment
    // coalesced store (full-cache-line writes; no L2 partial-line RMW).
    // C/D frag layout: row = (lane>>4)*4 + r, col = lane&15.
    #pragma unroll
    for (int j = 0; j < 4; ++j) {
        const int n  = wc * 64 + j * 16 + l15;
        const int gn = tileN + n;
        const float bn = bias[gn];
        const bool is_tanh = (gn < 1024);
        #pragma unroll
        for (int i = 0; i < 4; ++i) {
            const int rb = wr * 64 + i * 16 + hi * 4;
            #pragma unroll
            for (int r = 0; r < 4; ++r) {
                float v = acc[i][j][r] + bn;
                lds[(rb + r) * OT_STRIDE + n] =
                    (_Float16)(is_tanh ? fast_tanh(v) : fast_sigmoid(v));
            }
        }
    }
    __syncthreads();
    {
        const int row = tid >> 4;           // 0..15
        const int col = (tid & 15) * 8;     // 0..120
        #pragma unroll
        for (int itr = 0; itr < 8; ++itr) {
            const int rr = row + itr * 16;
            half8 vv = *(const half8*)(lds + rr * OT_STRIDE + col);
            *(half8*)(G + (size_t)(tileM + rr) * N_DIM + tileN + col) = vv;
        }
    }
}

// ---------------- chunked scan (G holds activated gates) ----------------
__global__ void k_scan1(const _Float16* __restrict__ G,
                        float* __restrict__ sumA, float* __restrict__ sumH) {
    const int chunk = blockIdx.x & 63;
    const int b     = blockIdx.x >> 6;
    const int d0    = threadIdx.x * 4;

    const _Float16* base = G + (size_t)(b * S_LEN + chunk * CLEN) * N_DIM;
    float A[4], H[4];
    #pragma unroll
    for (int j = 0; j < 4; ++j) { A[j] = 1.0f; H[j] = 0.0f; }
    #pragma unroll 4
    for (int s = 0; s < CLEN; ++s) {
        half4 v0 = *(const half4*)(base + (size_t)s * N_DIM + d0);
        half4 v1 = *(const half4*)(base + (size_t)s * N_DIM + 1024 + d0);
        #pragma unroll
        for (int j = 0; j < 4; ++j) {
            float g1 = (float)v1[j];
            float a  = 1.0f - g1;
            H[j] = fmaf(a, H[j], (float)v0[j] * g1);
            A[j] *= a;
        }
    }
    const int cidx = (b * NCHUNK + chunk) * 1024 + d0;
    *(float4*)(sumA + cidx) = make_float4(A[0], A[1], A[2], A[3]);
    *(float4*)(sumH + cidx) = make_float4(H[0], H[1], H[2], H[3]);
}

__global__ void k_scan2(const float* __restrict__ sumA, const float* __restrict__ sumH,
                        float* __restrict__ pref) {
    const int c = blockIdx.x * blockDim.x + threadIdx.x;  // 0..4095
    const int b = c >> 10;
    const int d = c & 1023;
    float h = 0.0f;
    #pragma unroll 8
    for (int chunk = 0; chunk < NCHUNK; ++chunk) {
        const int idx = (b * NCHUNK + chunk) * 1024 + d;
        pref[idx] = h;
        h = fmaf(sumA[idx], h, sumH[idx]);
    }
}

__global__ void k_scan3(const _Float16* __restrict__ G,
                        const float* __restrict__ pref,
                        float* __restrict__ out) {
    const int chunk = blockIdx.x & 63;
    const int b     = blockIdx.x >> 6;
    const int d0    = threadIdx.x * 4;

    const _Float16* base = G + (size_t)(b * S_LEN + chunk * CLEN) * N_DIM;
    const int cidx = (b * NCHUNK + chunk) * 1024 + d0;
    float h[4];
    #pragma unroll
    for (int j = 0; j < 4; ++j) h[j] = pref[cidx + j];

    #pragma unroll 4
    for (int s = 0; s < CLEN; ++s) {
        half4 v0 = *(const half4*)(base + (size_t)s * N_DIM + d0);
        half4 v1 = *(const half4*)(base + (size_t)s * N_DIM + 1024 + d0);
        half4 v2 = *(const half4*)(base + (size_t)s * N_DIM + 2048 + d0);
        float4 o;
        #pragma unroll
        for (int j = 0; j < 4; ++j) {
            float g1 = (float)v1[j];
            float a  = 1.0f - g1;
            h[j] = fmaf(a, h[j], (float)v0[j] * g1);
            ((float*)&o)[j] = fast_tanh(h[j]) * (float)v2[j];
        }
        *(float4*)(out + (size_t)(b * S_LEN + chunk * CLEN + s) * 1024 + d0) = o;
    }
}

extern "C" void kernel_launch(void* const* d_in, const int* in_sizes, int n_in,
                              void* d_out, int out_size, void* d_ws, size_t ws_size,
                              hipStream_t stream) {
    const float* x = (const float*)d_in[0];
    const float* W = (const float*)d_in[1];
    const float* b = (const float*)d_in[2];
    float* out = (float*)d_out;

    char* ws = (char*)d_ws;
    _Float16* xb = (_Float16*)ws;                               // 32 MB (dead after gemm)
    _Float16* Wt = (_Float16*)(ws + 33554432);                  // 6 MB
    _Float16* G  = (_Float16*)(ws + 33554432 + 6291456);        // 96 MB
    // Scan summaries alias xb's region (only live after k_gemm completes).
    float* sumA  = (float*)ws;                                  // 1 MB
    float* sumH  = sumA + 4096 * NCHUNK;                        // 1 MB
    float* pref  = sumH + 4096 * NCHUNK;                        // 1 MB

    k_cast <<<17152, 256, 0, stream>>>(x, xb, W, Wt);
    k_gemm <<<3072, 256, 0, stream>>>(xb, Wt, b, G);
    k_scan1<<<256, 256, 0, stream>>>(G, sumA, sumH);
    k_scan2<<<16,  256, 0, stream>>>(sumA, sumH, pref);
    k_scan3<<<256, 256, 0, stream>>>(G, pref, out);
    (void)in_sizes; (void)n_in; (void)out_size; (void)ws_size;
}

// Round 11
// 188.439 us; speedup vs baseline: 1.0348x; 1.0154x over previous
//
#include <hip/hip_runtime.h>
#include <hip/hip_bf16.h>
#include <cmath>

typedef _Float16 half8 __attribute__((ext_vector_type(8)));
typedef _Float16 half4 __attribute__((ext_vector_type(4)));
typedef float f32x4 __attribute__((ext_vector_type(4)));

// Geometry: B=4, S=4096, D=1024, D_H=1024 -> M=16384, K=1024, N=3072
#define M_DIM 16384
#define K_DIM 1024
#define N_DIM 3072
#define S_LEN 4096
#define NCHUNK 64
#define CLEN 64

#define OT_STRIDE 136   // epilogue LDS row stride (f16); 272B = 16B-aligned

__device__ __forceinline__ float fast_sigmoid(float x) {
    return __builtin_amdgcn_rcpf(1.0f + __expf(-x));
}
__device__ __forceinline__ float fast_tanh(float x) {
    float t = __expf(-2.0f * __builtin_fabsf(x));
    float y = (1.0f - t) * __builtin_amdgcn_rcpf(1.0f + t);
    return __builtin_copysignf(y, x);
}

// ---------------- fused cast kernel ----------------
// blocks [0,16384): x fp32 -> f16 (4 elems/thread)
// blocks [16384,17152): W (1024,3072) fp32 -> Wt (3072,1024) f16 via LDS transpose
__global__ void k_cast(const float* __restrict__ x, _Float16* __restrict__ xb,
                       const float* __restrict__ W, _Float16* __restrict__ Wt) {
    __shared__ float t[64][65];
    if (blockIdx.x < 16384) {
        int i = blockIdx.x * blockDim.x + threadIdx.x;
        float4 v = reinterpret_cast<const float4*>(x)[i];
        half4 h;
        h.x = (_Float16)v.x; h.y = (_Float16)v.y;
        h.z = (_Float16)v.z; h.w = (_Float16)v.w;
        reinterpret_cast<half4*>(xb)[i] = h;
    } else {
        const int wb = blockIdx.x - 16384;
        const int k0 = (wb / 48) * 64;
        const int n0 = (wb % 48) * 64;
        const int c  = threadIdx.x & 63;
        const int r0 = threadIdx.x >> 6;
        #pragma unroll
        for (int i = 0; i < 16; ++i) {
            int r = r0 + i * 4;
            t[r][c] = W[(size_t)(k0 + r) * N_DIM + n0 + c];
        }
        __syncthreads();
        #pragma unroll
        for (int i = 0; i < 16; ++i) {
            int r = r0 + i * 4;
            Wt[(size_t)(n0 + r) * K_DIM + k0 + c] = (_Float16)t[c][r];
        }
    }
}

// ---------------- GEMM: 128x128 tile, 4 waves, single 32KB buffer, 3 blocks/CU ----
// (256,3) NOT (256,4): unified VGPR+AGPR need ~140; cap 128 spills acc (round-6).
// At the m97-structure ceiling for K=1024 (~907 TF). Activations fused in epilogue.
// Round-11: 8x8 supertile ordering within each XCD's M-slab -> concurrent-block
// working set (A+B panels) ~fits 4MB L2 -> staging loads L2-hit, shorter drains.
__global__ __launch_bounds__(256, 3) void k_gemm(
    const _Float16* __restrict__ A,
    const _Float16* __restrict__ Bt,
    const float* __restrict__ bias,
    _Float16* __restrict__ G)
{
    __shared__ _Float16 lds[128 * OT_STRIDE];   // GEMM uses [0,16384); epilogue all

    const int tid  = threadIdx.x;
    const int lane = tid & 63;
    const int w    = tid >> 6;     // 0..3
    const int wr   = w >> 1;       // 0..1 (M half)
    const int wc   = w & 1;        // 0..1 (N half)

    // Bijective supertile map over [0,3072): bid -> (xcd, sm, sn, um, un).
    // Each XCD owns a 16M x 24N panel slab; within it, 8x8 supertiles.
    const int bid = blockIdx.x;
    const int xcd = bid & 7;
    const int t   = bid >> 3;            // 0..383
    const int sm  = t / 192;             // 0..1
    const int r_  = t - sm * 192;        // 0..191
    const int sn  = r_ >> 6;             // 0..2
    const int u   = r_ & 63;             // 0..63
    const int tileM = ((xcd << 4) + (sm << 3) + (u >> 3)) * 128;  // 128 M-panels
    const int tileN = (sn * 8 + (u & 7)) * 128;                   // 24 N-panels

    // Staging: LDS dest linear; global source column pre-swizzled (rule #21).
    const int l3   = lane >> 3;
    const int c8   = lane & 7;
    const int scol = ((c8 ^ l3) << 3);
    const _Float16* gA = A  + (size_t)(tileM + w * 32 + l3) * K_DIM + scol;
    const _Float16* gB = Bt + (size_t)(tileN + w * 32 + l3) * K_DIM + scol;
    _Float16* const sA = lds + w * 2048;
    _Float16* const sB = lds + 8192 + w * 2048;

    // Fragment reads: col-group ^ (row&7); row&7 == l15&7.
    const int l15 = lane & 15;
    const int hi  = lane >> 4;
    const int swz = (l15 & 7) << 3;
    const int o0  = (hi * 8)      ^ swz;
    const int o1  = (32 + hi * 8) ^ swz;
    const _Float16* arow = lds + (wr * 64 + l15) * 64;
    const _Float16* brow = lds + 8192 + (wc * 64 + l15) * 64;

    f32x4 acc[4][4] = {};

#define GL(SRC, DST) __builtin_amdgcn_global_load_lds( \
        (const __attribute__((address_space(1))) void*)(SRC), \
        (__attribute__((address_space(3))) void*)(DST), 16, 0, 0)

#define STAGE(kt) do { \
        const _Float16* ga_ = gA + (size_t)(kt) * 64; \
        const _Float16* gb_ = gB + (size_t)(kt) * 64; \
        GL(ga_,                       sA);        \
        GL(ga_ + (size_t) 8 * K_DIM,  sA + 512);  \
        GL(ga_ + (size_t)16 * K_DIM,  sA + 1024); \
        GL(ga_ + (size_t)24 * K_DIM,  sA + 1536); \
        GL(gb_,                       sB);        \
        GL(gb_ + (size_t) 8 * K_DIM,  sB + 512);  \
        GL(gb_ + (size_t)16 * K_DIM,  sB + 1024); \
        GL(gb_ + (size_t)24 * K_DIM,  sB + 1536); \
    } while (0)

#define SCHED0() __builtin_amdgcn_sched_barrier(0)

    // Prologue
    STAGE(0);
    asm volatile("s_waitcnt vmcnt(0)" ::: "memory");
    __builtin_amdgcn_s_barrier();
    asm volatile("" ::: "memory");

    #pragma unroll 1
    for (int kt = 0; kt < 16; ++kt) {
        half8 a[4][2], b[4][2];
        #pragma unroll
        for (int m = 0; m < 4; ++m) {
            a[m][0] = *(const half8*)(arow + m * 1024 + o0);
            a[m][1] = *(const half8*)(arow + m * 1024 + o1);
            b[m][0] = *(const half8*)(brow + m * 1024 + o0);
            b[m][1] = *(const half8*)(brow + m * 1024 + o1);
        }
        asm volatile("s_waitcnt lgkmcnt(0)" ::: "memory");
        SCHED0();
        __builtin_amdgcn_s_barrier();      // all waves done reading tile kt

        if (kt < 15) STAGE(kt + 1);        // overwrite buffer; lands under MFMA
        SCHED0();

        __builtin_amdgcn_s_setprio(1);
        #pragma unroll
        for (int m = 0; m < 4; ++m)
            #pragma unroll
            for (int n = 0; n < 4; ++n)
                acc[m][n] = __builtin_amdgcn_mfma_f32_16x16x32_f16(
                    a[m][0], b[n][0], acc[m][n], 0, 0, 0);
        #pragma unroll
        for (int m = 0; m < 4; ++m)
            #pragma unroll
            for (int n = 0; n < 4; ++n)
                acc[m][n] = __builtin_amdgcn_mfma_f32_16x16x32_f16(
                    a[m][1], b[n][1], acc[m][n], 0, 0, 0);
        __builtin_amdgcn_s_setprio(0);
        SCHED0();

        if (kt < 15) {
            asm volatile("s_waitcnt vmcnt(0)" ::: "memory");
            __builtin_amdgcn_s_barrier();  // tile kt+1 fully landed
            asm volatile("" ::: "memory");
        }
    }
#undef STAGE
#undef GL

    // Epilogue: bias + activation -> f16 into LDS, then full 256B-segment
    // coalesced store (full-cache-line writes; no L2 partial-line RMW).
    // C/D frag layout: row = (lane>>4)*4 + r, col = lane&15.
    #pragma unroll
    for (int j = 0; j < 4; ++j) {
        const int n  = wc * 64 + j * 16 + l15;
        const int gn = tileN + n;
        const float bn = bias[gn];
        const bool is_tanh = (gn < 1024);
        #pragma unroll
        for (int i = 0; i < 4; ++i) {
            const int rb = wr * 64 + i * 16 + hi * 4;
            #pragma unroll
            for (int r = 0; r < 4; ++r) {
                float v = acc[i][j][r] + bn;
                lds[(rb + r) * OT_STRIDE + n] =
                    (_Float16)(is_tanh ? fast_tanh(v) : fast_sigmoid(v));
            }
        }
    }
    __syncthreads();
    {
        const int row = tid >> 4;           // 0..15
        const int col = (tid & 15) * 8;     // 0..120
        #pragma unroll
        for (int itr = 0; itr < 8; ++itr) {
            const int rr = row + itr * 16;
            half8 vv = *(const half8*)(lds + rr * OT_STRIDE + col);
            *(half8*)(G + (size_t)(tileM + rr) * N_DIM + tileN + col) = vv;
        }
    }
}

// ---------------- chunked scan (G holds activated gates) ----------------
__global__ void k_scan1(const _Float16* __restrict__ G,
                        float* __restrict__ sumA, float* __restrict__ sumH) {
    const int chunk = blockIdx.x & 63;
    const int b     = blockIdx.x >> 6;
    const int d0    = threadIdx.x * 4;

    const _Float16* base = G + (size_t)(b * S_LEN + chunk * CLEN) * N_DIM;
    float A[4], H[4];
    #pragma unroll
    for (int j = 0; j < 4; ++j) { A[j] = 1.0f; H[j] = 0.0f; }
    #pragma unroll 4
    for (int s = 0; s < CLEN; ++s) {
        half4 v0 = *(const half4*)(base + (size_t)s * N_DIM + d0);
        half4 v1 = *(const half4*)(base + (size_t)s * N_DIM + 1024 + d0);
        #pragma unroll
        for (int j = 0; j < 4; ++j) {
            float g1 = (float)v1[j];
            float a  = 1.0f - g1;
            H[j] = fmaf(a, H[j], (float)v0[j] * g1);
            A[j] *= a;
        }
    }
    const int cidx = (b * NCHUNK + chunk) * 1024 + d0;
    *(float4*)(sumA + cidx) = make_float4(A[0], A[1], A[2], A[3]);
    *(float4*)(sumH + cidx) = make_float4(H[0], H[1], H[2], H[3]);
}

__global__ void k_scan2(const float* __restrict__ sumA, const float* __restrict__ sumH,
                        float* __restrict__ pref) {
    const int c = blockIdx.x * blockDim.x + threadIdx.x;  // 0..4095
    const int b = c >> 10;
    const int d = c & 1023;
    float h = 0.0f;
    #pragma unroll 8
    for (int chunk = 0; chunk < NCHUNK; ++chunk) {
        const int idx = (b * NCHUNK + chunk) * 1024 + d;
        pref[idx] = h;
        h = fmaf(sumA[idx], h, sumH[idx]);
    }
}

__global__ void k_scan3(const _Float16* __restrict__ G,
                        const float* __restrict__ pref,
                        float* __restrict__ out) {
    const int chunk = blockIdx.x & 63;
    const int b     = blockIdx.x >> 6;
    const int d0    = threadIdx.x * 4;

    const _Float16* base = G + (size_t)(b * S_LEN + chunk * CLEN) * N_DIM;
    const int cidx = (b * NCHUNK + chunk) * 1024 + d0;
    float h[4];
    #pragma unroll
    for (int j = 0; j < 4; ++j) h[j] = pref[cidx + j];

    #pragma unroll 4
    for (int s = 0; s < CLEN; ++s) {
        half4 v0 = *(const half4*)(base + (size_t)s * N_DIM + d0);
        half4 v1 = *(const half4*)(base + (size_t)s * N_DIM + 1024 + d0);
        half4 v2 = *(const half4*)(base + (size_t)s * N_DIM + 2048 + d0);
        float4 o;
        #pragma unroll
        for (int j = 0; j < 4; ++j) {
            float g1 = (float)v1[j];
            float a  = 1.0f - g1;
            h[j] = fmaf(a, h[j], (float)v0[j] * g1);
            ((float*)&o)[j] = fast_tanh(h[j]) * (float)v2[j];
        }
        *(float4*)(out + (size_t)(b * S_LEN + chunk * CLEN + s) * 1024 + d0) = o;
    }
}

extern "C" void kernel_launch(void* const* d_in, const int* in_sizes, int n_in,
                              void* d_out, int out_size, void* d_ws, size_t ws_size,
                              hipStream_t stream) {
    const float* x = (const float*)d_in[0];
    const float* W = (const float*)d_in[1];
    const float* b = (const float*)d_in[2];
    float* out = (float*)d_out;

    char* ws = (char*)d_ws;
    _Float16* xb = (_Float16*)ws;                               // 32 MB (dead after gemm)
    _Float16* Wt = (_Float16*)(ws + 33554432);                  // 6 MB
    _Float16* G  = (_Float16*)(ws + 33554432 + 6291456);        // 96 MB
    // Scan summaries alias xb's region (only live after k_gemm completes).
    float* sumA  = (float*)ws;                                  // 1 MB
    float* sumH  = sumA + 4096 * NCHUNK;                        // 1 MB
    float* pref  = sumH + 4096 * NCHUNK;                        // 1 MB

    k_cast <<<17152, 256, 0, stream>>>(x, xb, W, Wt);
    k_gemm <<<3072, 256, 0, stream>>>(xb, Wt, b, G);
    k_scan1<<<256, 256, 0, stream>>>(G, sumA, sumH);
    k_scan2<<<16,  256, 0, stream>>>(sumA, sumH, pref);
    k_scan3<<<256, 256, 0, stream>>>(G, pref, out);
    (void)in_sizes; (void)n_in; (void)out_size; (void)ws_size;
}